// Round 3
// baseline (844.269 us; speedup 1.0000x reference)
//
#include <hip/hip_runtime.h>
#include <hip/hip_bf16.h>
#include <cstdint>
#include <cstddef>

typedef __attribute__((ext_vector_type(8))) __bf16 bf16x8;
typedef __attribute__((ext_vector_type(4))) float f32x4;
typedef __attribute__((ext_vector_type(16))) float f32x16;

#define MFMA16(a, b, c) __builtin_amdgcn_mfma_f32_16x16x32_bf16((a), (b), (c), 0, 0, 0)
#define MFMA32(a, b, c) __builtin_amdgcn_mfma_f32_32x32x16_bf16((a), (b), (c), 0, 0, 0)

__device__ __forceinline__ bf16x8 cvt8(const float* __restrict__ p) {
    const float4 a = *(const float4*)p;
    const float4 b = *(const float4*)(p + 4);
    bf16x8 r;
    r[0] = (__bf16)a.x; r[1] = (__bf16)a.y; r[2] = (__bf16)a.z; r[3] = (__bf16)a.w;
    r[4] = (__bf16)b.x; r[5] = (__bf16)b.y; r[6] = (__bf16)b.z; r[7] = (__bf16)b.w;
    return r;
}

// ---------------------------------------------------------------------------
// K0a: x [2][4096][256] fp32  ->  xT [2][256][4096] bf16   (tile transpose)
// ---------------------------------------------------------------------------
__global__ __launch_bounds__(256) void k0a(const float* __restrict__ x,
                                           __bf16* __restrict__ xT) {
    __shared__ float tile[64][65];
    const int bid = blockIdx.x;
    const int b = bid >> 8;
    const int rem = bid & 255;
    const int tt = rem >> 2, dd = rem & 3;
    const int t0 = tt * 64, d0 = dd * 64;
    #pragma unroll
    for (int j = 0; j < 16; ++j) {
        int idx = j * 256 + threadIdx.x;
        int t = idx >> 6, d = idx & 63;
        tile[t][d] = x[((size_t)(b * 4096 + t0 + t)) * 256 + d0 + d];
    }
    __syncthreads();
    #pragma unroll
    for (int j = 0; j < 16; ++j) {
        int idx = j * 256 + threadIdx.x;
        int d = idx >> 6, t = idx & 63;
        xT[((size_t)(b * 256 + d0 + d)) * 4096 + t0 + t] = (__bf16)tile[t][d];
    }
}

// ---------------------------------------------------------------------------
// K0b: VO [8][256][256] fp32 -> VOT [256][2048] bf16, VOT[e][h*256+d] = VO[h][d][e]
// ---------------------------------------------------------------------------
__global__ __launch_bounds__(256) void k0b(const float* __restrict__ VO,
                                           __bf16* __restrict__ vot) {
    __shared__ float tile[64][65];
    const int bid = blockIdx.x;
    const int h = bid >> 4;
    const int rem = bid & 15;
    const int dt = rem >> 2, et = rem & 3;
    const int d0 = dt * 64, e0 = et * 64;
    #pragma unroll
    for (int j = 0; j < 16; ++j) {
        int idx = j * 256 + threadIdx.x;
        int d = idx >> 6, e = idx & 63;
        tile[d][e] = VO[((size_t)(h * 256 + d0 + d)) * 256 + e0 + e];
    }
    __syncthreads();
    #pragma unroll
    for (int j = 0; j < 16; ++j) {
        int idx = j * 256 + threadIdx.x;
        int e = idx >> 6, d = idx & 63;
        vot[((size_t)(e0 + e)) * 2048 + h * 256 + d0 + d] = (__bf16)tile[d][e];
    }
}

// ---------------------------------------------------------------------------
// proj: q[b,h,t,r] = sum_d x[b,t,d] * Q[h,r,d]  (and same for K)
// ---------------------------------------------------------------------------
__global__ __launch_bounds__(256) void proj_kernel(const float* __restrict__ x,
                                                   const float* __restrict__ Qw,
                                                   const float* __restrict__ Kw,
                                                   __bf16* __restrict__ qo,
                                                   __bf16* __restrict__ ko) {
    const int task = blockIdx.x * 4 + (threadIdx.x >> 6);
    const int l = threadIdx.x & 63;
    const int g = l >> 4, c = l & 15;
    const int tt = task >> 4;
    const int rem = task & 15;
    const int h = rem >> 1, s = rem & 1;
    const int tg = tt * 16;
    const float* W = s ? Kw : Qw;
    __bf16* outp = s ? ko : qo;

    f32x4 acc0 = {0.f, 0.f, 0.f, 0.f}, acc1 = {0.f, 0.f, 0.f, 0.f};
    #pragma unroll
    for (int kk = 0; kk < 8; ++kk) {
        bf16x8 a  = cvt8(&x[((size_t)(tg + c)) * 256 + kk * 32 + g * 8]);
        bf16x8 b0 = cvt8(&W[((size_t)(h * 32 + c)) * 256 + kk * 32 + g * 8]);
        bf16x8 b1 = cvt8(&W[((size_t)(h * 32 + 16 + c)) * 256 + kk * 32 + g * 8]);
        acc0 = MFMA16(a, b0, acc0);
        acc1 = MFMA16(a, b1, acc1);
    }
    const int b = tg >> 12, t = tg & 4095;
    const size_t obase = (size_t)(b * 8 + h) * 4096 + t;
    #pragma unroll
    for (int i = 0; i < 4; ++i) {
        outp[(obase + 4 * g + i) * 32 + c]      = (__bf16)acc0[i];
        outp[(obase + 4 * g + i) * 32 + 16 + c] = (__bf16)acc1[i];
    }
}

// ---------------------------------------------------------------------------
// attn v3: block = one (b,h) x 128 t-rows, 8 waves (512 thr).
//   Phase A: wave w -> softmax rows [w*16, w*16+16); P -> LDS (swizzled).
//   Phase B: wave w -> d-slice [w*32, w*32+32) of all 128 rows; 32x32 MFMA.
//   x-tile (256x64) single-buffered, staged via global_load_lds with
//   pre-swizzled global source; stage latency hidden under Phase A.
// grid = 512 blocks x 512 threads (exactly 2 blocks/CU resident)
// ---------------------------------------------------------------------------
__device__ __forceinline__ void stage_x(const __bf16* __restrict__ xTg_b,
                                        unsigned char* xbuf, int u0, int tid) {
    #pragma unroll
    for (int j = 0; j < 4; ++j) {
        int ch = j * 512 + tid;
        int d = ch >> 3;
        int slog = (ch & 7) ^ (d & 7);
        const __bf16* src = xTg_b + (size_t)d * 4096 + u0 + slog * 8;
        unsigned char* dst = xbuf + (size_t)(j * 512 + (tid & ~63)) * 16;  // wave-uniform
        __builtin_amdgcn_global_load_lds(
            (const __attribute__((address_space(1))) unsigned int*)src,
            (__attribute__((address_space(3))) unsigned int*)dst, 16, 0, 0);
    }
}

__device__ __forceinline__ void load_k(bf16x8 kreg[4], const __bf16* __restrict__ kg_bh,
                                       int u0, int c, int g) {
    #pragma unroll
    for (int ub = 0; ub < 4; ++ub)
        kreg[ub] = *(const bf16x8*)(kg_bh + (size_t)(u0 + ub * 16 + c) * 32 + g * 8);
}

__global__ __launch_bounds__(512, 4) void attn_kernel(const __bf16* __restrict__ qg,
                                                      const __bf16* __restrict__ kg,
                                                      const __bf16* __restrict__ xTg,
                                                      __bf16* __restrict__ ctx) {
    __shared__ __align__(16) unsigned char lds[32768 + 16384 + 512];
    unsigned char* xbuf = lds;
    unsigned char* pbuf = lds + 32768;
    float* scale_lds = (float*)(lds + 49152);

    const int bid = blockIdx.x;
    const int bh = bid >> 5;
    const int tt = bid & 31;
    const int b = bh >> 3, h = bh & 7;
    const int t0 = tt * 128;
    const int tid = threadIdx.x;
    const int w = tid >> 6;
    const int l = tid & 63;
    const int g = l >> 4, c = l & 15;
    const int l31 = l & 31, hi = l >> 5;

    const __bf16* xTg_b = xTg + (size_t)b * 256 * 4096;
    const __bf16* kg_bh = kg + (size_t)bh * 4096 * 32;

    // q A-fragment: this wave's 16 t-rows
    const bf16x8 qa = *(const bf16x8*)(qg + ((size_t)bh * 4096 + t0 + w * 16 + c) * 32 + g * 8);

    f32x16 acc[4];
    #pragma unroll
    for (int m = 0; m < 4; ++m)
        #pragma unroll
        for (int r = 0; r < 16; ++r) acc[m][r] = 0.f;
    float m2[4]   = {-3e38f, -3e38f, -3e38f, -3e38f};
    float lsum[4] = {0.f, 0.f, 0.f, 0.f};
    const float cl = 1.4426950408889634f / 16.0f;  // log2(e)/sqrt(D)

    bf16x8 kreg[4];
    load_k(kreg, kg_bh, 0, c, g);

    for (int ut = 0; ut < 64; ++ut) {
        __syncthreads();            // xbuf/pbuf free (prev Phase B done)
        stage_x(xTg_b, xbuf, ut * 64, tid);

        // ---- Phase A: scores + online softmax for this wave's 16 rows ----
        float pv[4][4];
        #pragma unroll
        for (int ub = 0; ub < 4; ++ub) {
            f32x4 s = MFMA16(qa, kreg[ub], ((f32x4){0.f, 0.f, 0.f, 0.f}));
            #pragma unroll
            for (int i = 0; i < 4; ++i) pv[ub][i] = s[i] * cl;
        }
        if (ut < 63) load_k(kreg, kg_bh, (ut + 1) * 64, c, g);  // prefetch

        float mx[4];
        #pragma unroll
        for (int i = 0; i < 4; ++i)
            mx[i] = fmaxf(fmaxf(pv[0][i], pv[1][i]), fmaxf(pv[2][i], pv[3][i]));
        #pragma unroll
        for (int dd = 1; dd < 16; dd <<= 1) {
            #pragma unroll
            for (int i = 0; i < 4; ++i) mx[i] = fmaxf(mx[i], __shfl_xor(mx[i], dd));
        }
        float scale[4], rs[4];
        #pragma unroll
        for (int i = 0; i < 4; ++i) {
            float mn = fmaxf(m2[i], mx[i]);
            scale[i] = __builtin_amdgcn_exp2f(m2[i] - mn);
            m2[i] = mn;
            rs[i] = 0.f;
        }
        #pragma unroll
        for (int ub = 0; ub < 4; ++ub) {
            #pragma unroll
            for (int i = 0; i < 4; ++i) {
                float p = __builtin_amdgcn_exp2f(pv[ub][i] - m2[i]);
                pv[ub][i] = p;
                rs[i] += p;
            }
        }
        #pragma unroll
        for (int dd = 1; dd < 16; dd <<= 1) {
            #pragma unroll
            for (int i = 0; i < 4; ++i) rs[i] += __shfl_xor(rs[i], dd);
        }
        #pragma unroll
        for (int i = 0; i < 4; ++i) lsum[i] = lsum[i] * scale[i] + rs[i];

        // write P (bf16, XOR-swizzled 128B rows) + per-row rescale factors
        #pragma unroll
        for (int ub = 0; ub < 4; ++ub) {
            #pragma unroll
            for (int i = 0; i < 4; ++i) {
                int row = w * 16 + 4 * g + i;
                int colb = (ub * 16 + c) * 2;
                *(__bf16*)(pbuf + row * 128 + (colb ^ ((row & 7) << 4))) = (__bf16)pv[ub][i];
            }
        }
        if (c < 4) scale_lds[w * 16 + 4 * g + c] = scale[c];
        __syncthreads();            // x staged (vmcnt drain) + P/scales visible

        // ---- Phase B: rescale + PV over this wave's 32-wide d-slice ----
        #pragma unroll
        for (int m = 0; m < 4; ++m) {
            f32x4 scm[4];
            bool allone = true;
            #pragma unroll
            for (int q = 0; q < 4; ++q) {
                scm[q] = *(const f32x4*)&scale_lds[m * 32 + q * 8 + hi * 4];
                allone = allone & (scm[q][0] == 1.f) & (scm[q][1] == 1.f) &
                         (scm[q][2] == 1.f) & (scm[q][3] == 1.f);
            }
            if (!__all(allone)) {
                #pragma unroll
                for (int r = 0; r < 16; ++r) acc[m][r] *= scm[r >> 2][r & 3];
            }
        }
        #pragma unroll
        for (int kt = 0; kt < 4; ++kt) {
            const int ub_byte = kt * 32 + hi * 16;
            bf16x8 pa[4], xb;
            #pragma unroll
            for (int m = 0; m < 4; ++m) {
                int row = m * 32 + l31;
                pa[m] = *(const bf16x8*)(pbuf + row * 128 + (ub_byte ^ ((row & 7) << 4)));
            }
            {
                int row = w * 32 + l31;
                xb = *(const bf16x8*)(xbuf + row * 128 + (ub_byte ^ ((row & 7) << 4)));
            }
            #pragma unroll
            for (int m = 0; m < 4; ++m) acc[m] = MFMA32(pa[m], xb, acc[m]);
        }
    }

    // ---- epilogue: share 1/lsum, normalize, store ctx[b][t][h][d] ----
    __syncthreads();
    if (c < 4) scale_lds[w * 16 + 4 * g + c] = 1.0f / lsum[c];
    __syncthreads();
    #pragma unroll
    for (int m = 0; m < 4; ++m) {
        f32x4 iv[4];
        #pragma unroll
        for (int q = 0; q < 4; ++q)
            iv[q] = *(const f32x4*)&scale_lds[m * 32 + q * 8 + hi * 4];
        #pragma unroll
        for (int r = 0; r < 16; ++r) {
            int t = t0 + m * 32 + (r & 3) + 8 * (r >> 2) + 4 * hi;
            int d = w * 32 + l31;
            ctx[((size_t)(b * 4096 + t) * 8 + h) * 256 + d] =
                (__bf16)(acc[m][r] * iv[r >> 2][r & 3]);
        }
    }
}

// ---------------------------------------------------------------------------
// gemm_out: out[bt][e] = sum_k ctx[bt][k] * VOT[e][k],  M=8192 K=2048 N=256
// block = one 32-row m-tile x all 256 e; wave w owns e-slice [w*32,(w+1)*32).
// A-panel read once per block (L1-broadcast across 8 waves).
// grid = 256 blocks x 512 threads
// ---------------------------------------------------------------------------
__global__ __launch_bounds__(512) void gemm_out(const __bf16* __restrict__ ctx,
                                                const __bf16* __restrict__ vot,
                                                float* __restrict__ out) {
    const int mt = blockIdx.x;
    const int w = threadIdx.x >> 6;
    const int l = threadIdx.x & 63;
    const int l31 = l & 31, hi = l >> 5;
    const size_t arow = (size_t)(mt * 32 + l31) * 2048;
    const size_t brow = (size_t)(w * 32 + l31) * 2048;
    f32x16 acc;
    #pragma unroll
    for (int r = 0; r < 16; ++r) acc[r] = 0.f;
    #pragma unroll 4
    for (int kk = 0; kk < 128; ++kk) {
        bf16x8 a = *(const bf16x8*)(ctx + arow + kk * 16 + hi * 8);
        bf16x8 b = *(const bf16x8*)(vot + brow + kk * 16 + hi * 8);
        acc = MFMA32(a, b, acc);
    }
    #pragma unroll
    for (int r = 0; r < 16; ++r) {
        int row = mt * 32 + (r & 3) + 8 * (r >> 2) + 4 * hi;
        out[(size_t)row * 256 + w * 32 + l31] = acc[r];
    }
}

// ---------------------------------------------------------------------------
extern "C" void kernel_launch(void* const* d_in, const int* in_sizes, int n_in,
                              void* d_out, int out_size, void* d_ws, size_t ws_size,
                              hipStream_t stream) {
    const float* x  = (const float*)d_in[0];  // [2][4096][256]
    const float* Qw = (const float*)d_in[1];  // [8][32][256]
    const float* Kw = (const float*)d_in[2];  // [8][32][256]
    const float* VO = (const float*)d_in[3];  // [8][256][256]
    float* out = (float*)d_out;               // [2][4096][256]

    char* ws = (char*)d_ws;
    __bf16* xT  = (__bf16*)(ws);                          // 4 MB  [2][256][4096]
    __bf16* qb  = (__bf16*)(ws + ((size_t)4 << 20));      // 4 MB  [2][8][4096][32]
    __bf16* kb  = (__bf16*)(ws + ((size_t)8 << 20));      // 4 MB
    __bf16* vot = (__bf16*)(ws + ((size_t)12 << 20));     // 1 MB  [256][2048]
    __bf16* ctx = (__bf16*)(ws + ((size_t)13 << 20));     // 32 MB [2][4096][8][256]

    k0a<<<512, 256, 0, stream>>>(x, xT);
    k0b<<<128, 256, 0, stream>>>(VO, vot);
    proj_kernel<<<2048, 256, 0, stream>>>(x, Qw, Kw, qb, kb);
    attn_kernel<<<512, 512, 0, stream>>>(qb, kb, xT, ctx);
    gemm_out<<<256, 512, 0, stream>>>(ctx, vot, out);
}

// Round 4
// 272.074 us; speedup vs baseline: 3.1031x; 3.1031x over previous
//
#include <hip/hip_runtime.h>
#include <hip/hip_bf16.h>
#include <cstdint>
#include <cstddef>

typedef __attribute__((ext_vector_type(8))) __bf16 bf16x8;
typedef __attribute__((ext_vector_type(4))) float f32x4;
typedef __attribute__((ext_vector_type(16))) float f32x16;

#define MFMA16(a, b, c) __builtin_amdgcn_mfma_f32_16x16x32_bf16((a), (b), (c), 0, 0, 0)
#define MFMA32(a, b, c) __builtin_amdgcn_mfma_f32_32x32x16_bf16((a), (b), (c), 0, 0, 0)

__device__ __forceinline__ bf16x8 cvt8(const float* __restrict__ p) {
    const float4 a = *(const float4*)p;
    const float4 b = *(const float4*)(p + 4);
    bf16x8 r;
    r[0] = (__bf16)a.x; r[1] = (__bf16)a.y; r[2] = (__bf16)a.z; r[3] = (__bf16)a.w;
    r[4] = (__bf16)b.x; r[5] = (__bf16)b.y; r[6] = (__bf16)b.z; r[7] = (__bf16)b.w;
    return r;
}

__device__ __forceinline__ f32x16 zf16() {
    f32x16 z;
    #pragma unroll
    for (int r = 0; r < 16; ++r) z[r] = 0.f;
    return z;
}

__device__ __forceinline__ unsigned pk2(float lo, float hi) {
    unsigned w;
    asm("v_cvt_pk_bf16_f32 %0, %1, %2" : "=v"(w) : "v"(lo), "v"(hi));
    return w;
}
__device__ __forceinline__ void swap32(unsigned& a, unsigned& b) {
    asm("v_permlane32_swap_b32 %0, %1" : "+v"(a), "+v"(b));
}
__device__ __forceinline__ bf16x8 mkfrag(unsigned a, unsigned b, unsigned c, unsigned d) {
    union { unsigned u[4]; bf16x8 v; } x;
    x.u[0] = a; x.u[1] = b; x.u[2] = c; x.u[3] = d;
    return x.v;
}

// ---------------------------------------------------------------------------
// K0a: x [2][4096][256] fp32  ->  xT [2][256][4096] bf16   (tile transpose)
// ---------------------------------------------------------------------------
__global__ __launch_bounds__(256) void k0a(const float* __restrict__ x,
                                           __bf16* __restrict__ xT) {
    __shared__ float tile[64][65];
    const int bid = blockIdx.x;
    const int b = bid >> 8;
    const int rem = bid & 255;
    const int tt = rem >> 2, dd = rem & 3;
    const int t0 = tt * 64, d0 = dd * 64;
    #pragma unroll
    for (int j = 0; j < 16; ++j) {
        int idx = j * 256 + threadIdx.x;
        int t = idx >> 6, d = idx & 63;
        tile[t][d] = x[((size_t)(b * 4096 + t0 + t)) * 256 + d0 + d];
    }
    __syncthreads();
    #pragma unroll
    for (int j = 0; j < 16; ++j) {
        int idx = j * 256 + threadIdx.x;
        int d = idx >> 6, t = idx & 63;
        xT[((size_t)(b * 256 + d0 + d)) * 4096 + t0 + t] = (__bf16)tile[t][d];
    }
}

// ---------------------------------------------------------------------------
// K0b: VO [8][256][256] fp32 -> VOT [256][2048] bf16, VOT[e][h*256+d] = VO[h][d][e]
// ---------------------------------------------------------------------------
__global__ __launch_bounds__(256) void k0b(const float* __restrict__ VO,
                                           __bf16* __restrict__ vot) {
    __shared__ float tile[64][65];
    const int bid = blockIdx.x;
    const int h = bid >> 4;
    const int rem = bid & 15;
    const int dt = rem >> 2, et = rem & 3;
    const int d0 = dt * 64, e0 = et * 64;
    #pragma unroll
    for (int j = 0; j < 16; ++j) {
        int idx = j * 256 + threadIdx.x;
        int d = idx >> 6, e = idx & 63;
        tile[d][e] = VO[((size_t)(h * 256 + d0 + d)) * 256 + e0 + e];
    }
    __syncthreads();
    #pragma unroll
    for (int j = 0; j < 16; ++j) {
        int idx = j * 256 + threadIdx.x;
        int e = idx >> 6, d = idx & 63;
        vot[((size_t)(e0 + e)) * 2048 + h * 256 + d0 + d] = (__bf16)tile[d][e];
    }
}

// ---------------------------------------------------------------------------
// proj: q[b,h,t,r] = sum_d x[b,t,d] * Q[h,r,d]  (and same for K)
// ---------------------------------------------------------------------------
__global__ __launch_bounds__(256) void proj_kernel(const float* __restrict__ x,
                                                   const float* __restrict__ Qw,
                                                   const float* __restrict__ Kw,
                                                   __bf16* __restrict__ qo,
                                                   __bf16* __restrict__ ko) {
    const int task = blockIdx.x * 4 + (threadIdx.x >> 6);
    const int l = threadIdx.x & 63;
    const int g = l >> 4, c = l & 15;
    const int tt = task >> 4;
    const int rem = task & 15;
    const int h = rem >> 1, s = rem & 1;
    const int tg = tt * 16;
    const float* W = s ? Kw : Qw;
    __bf16* outp = s ? ko : qo;

    f32x4 acc0 = {0.f, 0.f, 0.f, 0.f}, acc1 = {0.f, 0.f, 0.f, 0.f};
    #pragma unroll
    for (int kk = 0; kk < 8; ++kk) {
        bf16x8 a  = cvt8(&x[((size_t)(tg + c)) * 256 + kk * 32 + g * 8]);
        bf16x8 b0 = cvt8(&W[((size_t)(h * 32 + c)) * 256 + kk * 32 + g * 8]);
        bf16x8 b1 = cvt8(&W[((size_t)(h * 32 + 16 + c)) * 256 + kk * 32 + g * 8]);
        acc0 = MFMA16(a, b0, acc0);
        acc1 = MFMA16(a, b1, acc1);
    }
    const int b = tg >> 12, t = tg & 4095;
    const size_t obase = (size_t)(b * 8 + h) * 4096 + t;
    #pragma unroll
    for (int i = 0; i < 4; ++i) {
        outp[(obase + 4 * g + i) * 32 + c]      = (__bf16)acc0[i];
        outp[(obase + 4 * g + i) * 32 + 16 + c] = (__bf16)acc1[i];
    }
}

// ---------------------------------------------------------------------------
// attn v4 (m214-style): block = one (b,h) x 256 t-rows, 8 waves (512 thr).
//   Wave owns 32 q-rows end-to-end. Swapped QK^T: S^T = mfma(K,Q) so the
//   P-row is lane-local (q = lane&31). Softmax in-register; P -> A-frags via
//   cvt_pk_bf16 + permlane32_swap (T12). Defer-max rescale (T13, THR=8).
//   x-tile [256d][64u] double-buffered in LDS via global_load_lds with
//   pre-swizzled source; one barrier per u-tile.
// grid = 256 blocks x 512 threads (1 block/CU)
// ---------------------------------------------------------------------------
__device__ __forceinline__ void stage_x(const __bf16* __restrict__ xTg_b,
                                        unsigned char* xbuf, int u0, int tid) {
    #pragma unroll
    for (int j = 0; j < 4; ++j) {
        int ch = j * 512 + tid;
        int d = ch >> 3;
        int slog = (ch & 7) ^ (d & 7);
        const __bf16* src = xTg_b + (size_t)d * 4096 + u0 + slog * 8;
        unsigned char* dst = xbuf + (size_t)(j * 512 + (tid & ~63)) * 16;  // wave-uniform
        __builtin_amdgcn_global_load_lds(
            (const __attribute__((address_space(1))) unsigned int*)src,
            (__attribute__((address_space(3))) unsigned int*)dst, 16, 0, 0);
    }
}

#define MKFRAG(dst, V, base)                                   \
    {                                                          \
        unsigned wa = pk2(V[(base) + 0], V[(base) + 1]);       \
        unsigned wb = pk2(V[(base) + 2], V[(base) + 3]);       \
        unsigned wc = pk2(V[(base) + 4], V[(base) + 5]);       \
        unsigned wd = pk2(V[(base) + 6], V[(base) + 7]);       \
        swap32(wa, wc);                                        \
        swap32(wb, wd);                                        \
        dst = mkfrag(wa, wb, wc, wd);                          \
    }

__global__ __launch_bounds__(512, 2) void attn_kernel(const __bf16* __restrict__ qg,
                                                      const __bf16* __restrict__ kg,
                                                      const __bf16* __restrict__ xTg,
                                                      __bf16* __restrict__ ctx) {
    __shared__ __align__(16) unsigned char lds[65536 + 1024];
    unsigned char* xbuf0 = lds;
    unsigned char* xbuf1 = lds + 32768;

    const int bid = blockIdx.x;
    const int bh = bid >> 4;         // 16 (b,h) pairs
    const int tt = bid & 15;         // 16 t-chunks of 256
    const int b = bh >> 3, h = bh & 7;
    const int t0 = tt * 256;
    const int tid = threadIdx.x;
    const int w = tid >> 6;
    const int l = tid & 63;
    const int l31 = l & 31, hi = l >> 5;

    float* scale_w = (float*)(lds + 65536) + w * 32;   // per-wave region

    const __bf16* xTg_b = xTg + (size_t)b * 256 * 4096;
    const __bf16* kg_bh = kg + (size_t)bh * 4096 * 32;

    // Q B-fragments for this wave's 32 q-rows (q = l31), r = step*16 + hi*8 + j
    const size_t qoff = ((size_t)bh * 4096 + t0 + w * 32 + l31) * 32;
    const bf16x8 qf0 = *(const bf16x8*)(qg + qoff + hi * 8);
    const bf16x8 qf1 = *(const bf16x8*)(qg + qoff + 16 + hi * 8);

    f32x16 acc[8];
    #pragma unroll
    for (int n = 0; n < 8; ++n)
        #pragma unroll
        for (int r = 0; r < 16; ++r) acc[n][r] = 0.f;

    float m_run = -3.0e38f, lsum = 0.f;
    const float cl = 1.4426950408889634f / 16.0f;  // log2(e)/sqrt(D)

    // K A-fragments for u-tile 0: kA[sub u0/u32][kstep]
    bf16x8 kA[2][2];
    #pragma unroll
    for (int s = 0; s < 2; ++s)
        #pragma unroll
        for (int st = 0; st < 2; ++st)
            kA[s][st] = *(const bf16x8*)(kg_bh + (size_t)(s * 32 + l31) * 32 + st * 16 + hi * 8);

    stage_x(xTg_b, xbuf0, 0, tid);
    __syncthreads();

    const int swz = (l31 & 7) << 4;

    for (int ut = 0; ut < 64; ++ut) {
        unsigned char* xcur = (ut & 1) ? xbuf1 : xbuf0;
        unsigned char* xnxt = (ut & 1) ? xbuf0 : xbuf1;
        if (ut < 63) stage_x(xTg_b, xnxt, (ut + 1) * 64, tid);

        // ---- S^T = K * Q^T  (m=u, n=q=l31, k=r over two 16-steps) ----
        f32x16 s0 = MFMA32(kA[0][0], qf0, zf16());
        s0 = MFMA32(kA[0][1], qf1, s0);
        f32x16 s1 = MFMA32(kA[1][0], qf0, zf16());
        s1 = MFMA32(kA[1][1], qf1, s1);

        if (ut < 63) {  // prefetch next k-tile fragments
            const __bf16* kp = kg_bh + (size_t)(ut + 1) * 64 * 32;
            #pragma unroll
            for (int s = 0; s < 2; ++s)
                #pragma unroll
                for (int st = 0; st < 2; ++st)
                    kA[s][st] = *(const bf16x8*)(kp + (size_t)(s * 32 + l31) * 32 + st * 16 + hi * 8);
        }

        // ---- online softmax, fully per-lane (row q = l31) ----
        float pm = s0[0];
        #pragma unroll
        for (int r = 1; r < 16; ++r) pm = fmaxf(pm, s0[r]);
        #pragma unroll
        for (int r = 0; r < 16; ++r) pm = fmaxf(pm, s1[r]);
        pm = fmaxf(pm, __shfl_xor(pm, 32));
        const float mc = pm * cl;
        float scale = 1.f;
        const bool doresc = __any(!(mc <= m_run + 8.f));  // T13 defer-max
        if (doresc) {
            float mn = fmaxf(m_run, mc);
            scale = __builtin_amdgcn_exp2f(m_run - mn);
            m_run = mn;
        }
        float rs = 0.f;
        #pragma unroll
        for (int r = 0; r < 16; ++r) {
            float p = __builtin_amdgcn_exp2f(s0[r] * cl - m_run);
            s0[r] = p; rs += p;
        }
        #pragma unroll
        for (int r = 0; r < 16; ++r) {
            float p = __builtin_amdgcn_exp2f(s1[r] * cl - m_run);
            s1[r] = p; rs += p;
        }
        rs += __shfl_xor(rs, 32);
        lsum = lsum * scale + rs;

        if (doresc) {  // rare: broadcast scale by q-row via per-wave LDS, rescale acc
            if (!hi) scale_w[l31] = scale;
            f32x4 sv[4];
            #pragma unroll
            for (int q4 = 0; q4 < 4; ++q4)
                sv[q4] = *(const f32x4*)&scale_w[q4 * 8 + hi * 4];
            #pragma unroll
            for (int n = 0; n < 8; ++n)
                #pragma unroll
                for (int r = 0; r < 16; ++r) acc[n][r] *= sv[r >> 2][r & 3];
        }

        // ---- P (C-layout) -> 4 A-frags via cvt_pk + permlane32_swap (T12) ----
        bf16x8 pf0, pf1, pf2, pf3;
        MKFRAG(pf0, s0, 0);
        MKFRAG(pf1, s0, 8);
        MKFRAG(pf2, s1, 0);
        MKFRAG(pf3, s1, 8);

        // ---- PV: acc[n] += P[q][u-tile] * x[u][d-tile n] ----
        #pragma unroll
        for (int kk = 0; kk < 4; ++kk) {
            const bf16x8 pa = (kk == 0) ? pf0 : (kk == 1) ? pf1 : (kk == 2) ? pf2 : pf3;
            #pragma unroll
            for (int n = 0; n < 8; ++n) {
                const bf16x8 xb = *(const bf16x8*)(xcur + (n * 32 + l31) * 128 +
                                                   ((kk * 32 + hi * 16) ^ swz));
                acc[n] = MFMA32(pa, xb, acc[n]);
            }
        }
        __syncthreads();   // PV reads done; next x-stage drained (vmcnt 0)
    }

    // ---- epilogue: broadcast 1/lsum by q-row, normalize, store ----
    const float linv = 1.0f / lsum;
    if (!hi) scale_w[l31] = linv;
    f32x4 iv[4];
    #pragma unroll
    for (int q4 = 0; q4 < 4; ++q4)
        iv[q4] = *(const f32x4*)&scale_w[q4 * 8 + hi * 4];
    #pragma unroll
    for (int n = 0; n < 8; ++n) {
        #pragma unroll
        for (int r = 0; r < 16; ++r) {
            int t = t0 + w * 32 + (r & 3) + 8 * (r >> 2) + 4 * hi;
            int d = n * 32 + l31;
            ctx[((size_t)(b * 4096 + t) * 8 + h) * 256 + d] =
                (__bf16)(acc[n][r] * iv[r >> 2][r & 3]);
        }
    }
}

// ---------------------------------------------------------------------------
// gemm_out: out[bt][e] = sum_k ctx[bt][k] * VOT[e][k],  M=8192 K=2048 N=256
// block = one 32-row m-tile x all 256 e; wave w owns e-slice [w*32,(w+1)*32).
// ---------------------------------------------------------------------------
__global__ __launch_bounds__(512) void gemm_out(const __bf16* __restrict__ ctx,
                                                const __bf16* __restrict__ vot,
                                                float* __restrict__ out) {
    const int mt = blockIdx.x;
    const int w = threadIdx.x >> 6;
    const int l = threadIdx.x & 63;
    const int l31 = l & 31, hi = l >> 5;
    const size_t arow = (size_t)(mt * 32 + l31) * 2048;
    const size_t brow = (size_t)(w * 32 + l31) * 2048;
    f32x16 acc;
    #pragma unroll
    for (int r = 0; r < 16; ++r) acc[r] = 0.f;
    #pragma unroll 4
    for (int kk = 0; kk < 128; ++kk) {
        bf16x8 a = *(const bf16x8*)(ctx + arow + kk * 16 + hi * 8);
        bf16x8 b = *(const bf16x8*)(vot + brow + kk * 16 + hi * 8);
        acc = MFMA32(a, b, acc);
    }
    #pragma unroll
    for (int r = 0; r < 16; ++r) {
        int row = mt * 32 + (r & 3) + 8 * (r >> 2) + 4 * hi;
        out[(size_t)row * 256 + w * 32 + l31] = acc[r];
    }
}

// ---------------------------------------------------------------------------
extern "C" void kernel_launch(void* const* d_in, const int* in_sizes, int n_in,
                              void* d_out, int out_size, void* d_ws, size_t ws_size,
                              hipStream_t stream) {
    const float* x  = (const float*)d_in[0];  // [2][4096][256]
    const float* Qw = (const float*)d_in[1];  // [8][32][256]
    const float* Kw = (const float*)d_in[2];  // [8][32][256]
    const float* VO = (const float*)d_in[3];  // [8][256][256]
    float* out = (float*)d_out;               // [2][4096][256]

    char* ws = (char*)d_ws;
    __bf16* xT  = (__bf16*)(ws);                          // 4 MB  [2][256][4096]
    __bf16* qb  = (__bf16*)(ws + ((size_t)4 << 20));      // 4 MB  [2][8][4096][32]
    __bf16* kb  = (__bf16*)(ws + ((size_t)8 << 20));      // 4 MB
    __bf16* vot = (__bf16*)(ws + ((size_t)12 << 20));     // 1 MB  [256][2048]
    __bf16* ctx = (__bf16*)(ws + ((size_t)13 << 20));     // 32 MB [2][4096][8][256]

    k0a<<<512, 256, 0, stream>>>(x, xT);
    k0b<<<128, 256, 0, stream>>>(VO, vot);
    proj_kernel<<<2048, 256, 0, stream>>>(x, Qw, Kw, qb, kb);
    attn_kernel<<<256, 512, 0, stream>>>(qb, kb, xT, ctx);
    gemm_out<<<256, 512, 0, stream>>>(ctx, vot, out);
}